// Round 3
// baseline (1280.634 us; speedup 1.0000x reference)
//
#include <hip/hip_runtime.h>

#define D_MODEL 1024
#define N_HEADS 16
#define D_K     64
#define BB      2
#define SS      2048
#define M_TOT   (BB * SS)          // 4096

typedef __attribute__((ext_vector_type(8))) short short8;
typedef __attribute__((ext_vector_type(4))) float f32x4;

// ---------------------------------------------------------------------------
// fp32 -> (hi, lo) bf16 split.  x ~= hi + lo with residual ~2^-17 |x|.
// ---------------------------------------------------------------------------
__device__ __forceinline__ unsigned short bf_rne(float x) {
    unsigned u = __builtin_bit_cast(unsigned, x);
    u += 0x7fff + ((u >> 16) & 1);
    return (unsigned short)(u >> 16);
}
__device__ __forceinline__ void split2(float x, unsigned short& h, unsigned short& l) {
    unsigned short hh = bf_rne(x);
    float hf = __builtin_bit_cast(float, ((unsigned)hh) << 16);
    l = bf_rne(x - hf);
    h = hh;
}

// LDS swizzle: bf16 tile row r (64 elems); XOR 16B-chunk index with (r&7).
__device__ __forceinline__ int swz(int r, int k) {
    return r * 64 + ((((k >> 3) ^ (r & 7)) << 3) | (k & 7));
}

// ---------------------------------------------------------------------------
// Elementwise fp32 -> split-bf16 planes (weights).
// ---------------------------------------------------------------------------
__global__ __launch_bounds__(256) void split_f32(
    const float* __restrict__ in, unsigned short* __restrict__ h,
    unsigned short* __restrict__ l, int n4)
{
    int i = blockIdx.x * 256 + threadIdx.x;
    if (i >= n4) return;
    float4 v = ((const float4*)in)[i];
    unsigned short hh[4], ll[4];
    split2(v.x, hh[0], ll[0]); split2(v.y, hh[1], ll[1]);
    split2(v.z, hh[2], ll[2]); split2(v.w, hh[3], ll[3]);
    *(ushort4*)&h[i * 4] = make_ushort4(hh[0], hh[1], hh[2], hh[3]);
    *(ushort4*)&l[i * 4] = make_ushort4(ll[0], ll[1], ll[2], ll[3]);
}

// ---------------------------------------------------------------------------
// bf16x3-split MFMA GEMM:  C = (A @ B^T) [+ bias]
//   A: fp32 [M,K], converted to hi/lo during staging. B: pre-split planes.
// STORE: 0 fp32 [m*ldc+n]               (out-projection)
//        2 split head-split [b,h,s,d]   (qh / kh planes)
//        3 split head-T     [b,h,d,s]   (vht planes)
// ---------------------------------------------------------------------------
template <int STORE, bool BIAS>
__global__ __launch_bounds__(256, 2) void gemm3(
    const float* __restrict__ A, int lda,
    const unsigned short* __restrict__ Bh, const unsigned short* __restrict__ Bl,
    int ldb,
    const float* __restrict__ bias,
    float* __restrict__ Cf, unsigned short* __restrict__ Ch,
    unsigned short* __restrict__ Cl,
    int ldc, int K)
{
    const int m0 = blockIdx.y * 128;
    const int n0 = blockIdx.x * 128;
    const int t  = threadIdx.x;
    const int lane = t & 63;
    const int wy = t >> 7;
    const int wx = (t >> 6) & 1;

    __shared__ __align__(16) unsigned short Ahs[128 * 64];
    __shared__ __align__(16) unsigned short Als[128 * 64];
    __shared__ __align__(16) unsigned short Bhs[128 * 64];
    __shared__ __align__(16) unsigned short Bls[128 * 64];

    const int sr = t >> 3;
    const int sc = (t & 7) * 8;

    f32x4 acc[4][4];
#pragma unroll
    for (int i = 0; i < 4; ++i)
#pragma unroll
        for (int j = 0; j < 4; ++j) acc[i][j] = (f32x4){0.f, 0.f, 0.f, 0.f};

    for (int k0 = 0; k0 < K; k0 += 64) {
        float4 a0[4], a1[4];
#pragma unroll
        for (int p = 0; p < 4; ++p) {
            const float* s = &A[(long)(m0 + sr + 32 * p) * lda + k0 + sc];
            a0[p] = *(const float4*)s;
            a1[p] = *(const float4*)(s + 4);
        }
        short8 gbh[4], gbl[4];
#pragma unroll
        for (int p = 0; p < 4; ++p) {
            const long bo = (long)(n0 + sr + 32 * p) * ldb + k0 + sc;
            gbh[p] = *(const short8*)&Bh[bo];
            gbl[p] = *(const short8*)&Bl[bo];
        }
        __syncthreads();
#pragma unroll
        for (int p = 0; p < 4; ++p) {
            union { short8 v; unsigned short u[8]; } ph, pl;
            float f[8] = {a0[p].x, a0[p].y, a0[p].z, a0[p].w,
                          a1[p].x, a1[p].y, a1[p].z, a1[p].w};
#pragma unroll
            for (int e = 0; e < 8; ++e) split2(f[e], ph.u[e], pl.u[e]);
            const int idx = swz(sr + 32 * p, sc);
            *(short8*)&Ahs[idx] = ph.v;
            *(short8*)&Als[idx] = pl.v;
            *(short8*)&Bhs[idx] = gbh[p];
            *(short8*)&Bls[idx] = gbl[p];
        }
        __syncthreads();

#pragma unroll
        for (int ks = 0; ks < 2; ++ks) {
            const int fr = lane & 15;
            const int fk = ks * 32 + (lane >> 4) * 8;
            short8 ah[4], al[4], bh8[4], bl8[4];
#pragma unroll
            for (int i = 0; i < 4; ++i) {
                const int idx = swz(wy * 64 + i * 16 + fr, fk);
                ah[i] = *(const short8*)&Ahs[idx];
                al[i] = *(const short8*)&Als[idx];
            }
#pragma unroll
            for (int j = 0; j < 4; ++j) {
                const int idx = swz(wx * 64 + j * 16 + fr, fk);
                bh8[j] = *(const short8*)&Bhs[idx];
                bl8[j] = *(const short8*)&Bls[idx];
            }
#pragma unroll
            for (int i = 0; i < 4; ++i)
#pragma unroll
                for (int j = 0; j < 4; ++j) {
                    acc[i][j] = __builtin_amdgcn_mfma_f32_16x16x32_bf16(ah[i], bh8[j], acc[i][j], 0, 0, 0);
                    acc[i][j] = __builtin_amdgcn_mfma_f32_16x16x32_bf16(al[i], bh8[j], acc[i][j], 0, 0, 0);
                    acc[i][j] = __builtin_amdgcn_mfma_f32_16x16x32_bf16(ah[i], bl8[j], acc[i][j], 0, 0, 0);
                }
        }
    }

    const int fr = lane & 15;
    const int fq = lane >> 4;
#pragma unroll
    for (int j = 0; j < 4; ++j) {
        const int n = n0 + wx * 64 + j * 16 + fr;
        const float bj = BIAS ? bias[n] : 0.0f;
#pragma unroll
        for (int i = 0; i < 4; ++i)
#pragma unroll
            for (int r = 0; r < 4; ++r) {
                const int m = m0 + wy * 64 + i * 16 + fq * 4 + r;
                const float val = acc[i][j][r] + bj;
                if (STORE == 0) {
                    Cf[(long)m * ldc + n] = val;
                } else if (STORE == 2) {
                    const int b = m >> 11, s = m & 2047, h = n >> 6, d = n & 63;
                    unsigned short hh, ll; split2(val, hh, ll);
                    const long idx = (((long)(b * N_HEADS + h)) * SS + s) * 64 + d;
                    Ch[idx] = hh; Cl[idx] = ll;
                } else {  // STORE 3
                    const int b = m >> 11, s = m & 2047, h = n >> 6, d = n & 63;
                    unsigned short hh, ll; split2(val, hh, ll);
                    const long idx = (((long)(b * N_HEADS + h)) * 64 + d) * SS + s;
                    Ch[idx] = hh; Cl[idx] = ll;
                }
            }
    }
}

// ---------------------------------------------------------------------------
// Fused scores + softmax + PV with RECOMPUTE (no raw-S spill).
// One block = 128 q-rows of one (b,h).  j-tile = 64.
//   pass A: S tiles via MFMA (Q in regs, K via LDS), exact online (m,l) only.
//   reduce: combine (m,l) across lanes and the two wx-waves.
//   pass B: recompute S tile (bitwise-identical), p = exp(s-m)*rl,
//           write final attn; transpose P via u32-packed LDS (hi|lo<<16),
//           O += P V via MFMA (V B-frags direct from global, L2-hot).
// grid: x = z (same-XCD grouping: gridDim.x=32, 32%8==0), y = m-tile.
// ---------------------------------------------------------------------------
__global__ __launch_bounds__(256, 2) void attn_fused(
    const unsigned short* __restrict__ qh_hi, const unsigned short* __restrict__ qh_lo,
    const unsigned short* __restrict__ kh_hi, const unsigned short* __restrict__ kh_lo,
    const unsigned short* __restrict__ vt_hi, const unsigned short* __restrict__ vt_lo,
    float* __restrict__ attn, float* __restrict__ oh)
{
    const int z  = blockIdx.x;
    const int m0 = blockIdx.y * 128;
    const int b  = z >> 4;
    const int h  = z & 15;
    const int t  = threadIdx.x;
    const int lane = t & 63;
    const int wy = t >> 7;          // m 64-half
    const int wx = (t >> 6) & 1;    // j/d half
    const int fr = lane & 15;
    const int fg = lane >> 4;

    __shared__ __align__(16) unsigned short Kh[64 * 64];
    __shared__ __align__(16) unsigned short Kl[64 * 64];
    __shared__ __align__(16) unsigned int   Pb[128 * 64];   // p packed hi|lo<<16
    __shared__ float red_m[2][128];
    __shared__ float red_l[2][128];
    __shared__ float sm_m[128];
    __shared__ float sm_rl[128];

    float* attnZ = attn + (long)z * SS * SS;

    // ---- Q fragments resident in registers (16B contiguous in d) ----
    short8 qa_h[2][4], qa_l[2][4];
#pragma unroll
    for (int ks = 0; ks < 2; ++ks)
#pragma unroll
        for (int i = 0; i < 4; ++i) {
            const long g = ((long)z * SS + m0 + wy * 64 + i * 16 + fr) * 64 + ks * 32 + fg * 8;
            qa_h[ks][i] = *(const short8*)&qh_hi[g];
            qa_l[ks][i] = *(const short8*)&qh_lo[g];
        }

    // K staging indices: row = t>>2 (0..63), kc = (t&3)*16 (+8 for 2nd chunk)
    const int krow = t >> 2;
    const int kc   = (t & 3) * 16;

    float m_reg[16], l_reg[16];
#pragma unroll
    for (int e = 0; e < 16; ++e) { m_reg[e] = -3.0e38f; l_reg[e] = 0.f; }

    // ------------------------- pass A: (m,l) only -------------------------
    for (int nt = 0; nt < 32; ++nt) {
        const int j0 = nt * 64;
        const long gk = ((long)z * SS + j0 + krow) * 64 + kc;
        const short8 g0h = *(const short8*)&kh_hi[gk];
        const short8 g1h = *(const short8*)&kh_hi[gk + 8];
        const short8 g0l = *(const short8*)&kh_lo[gk];
        const short8 g1l = *(const short8*)&kh_lo[gk + 8];
        *(short8*)&Kh[swz(krow, kc)]     = g0h;
        *(short8*)&Kh[swz(krow, kc + 8)] = g1h;
        *(short8*)&Kl[swz(krow, kc)]     = g0l;
        *(short8*)&Kl[swz(krow, kc + 8)] = g1l;
        __syncthreads();

        f32x4 acc[4][2];
#pragma unroll
        for (int i = 0; i < 4; ++i) { acc[i][0] = (f32x4){0,0,0,0}; acc[i][1] = (f32x4){0,0,0,0}; }

#pragma unroll
        for (int ks = 0; ks < 2; ++ks) {
            const int fk = ks * 32 + fg * 8;
            short8 bh8[2], bl8[2];
#pragma unroll
            for (int jf = 0; jf < 2; ++jf) {
                const int idx = swz(wx * 32 + jf * 16 + fr, fk);
                bh8[jf] = *(const short8*)&Kh[idx];
                bl8[jf] = *(const short8*)&Kl[idx];
            }
#pragma unroll
            for (int i = 0; i < 4; ++i)
#pragma unroll
                for (int jf = 0; jf < 2; ++jf) {
                    acc[i][jf] = __builtin_amdgcn_mfma_f32_16x16x32_bf16(qa_h[ks][i], bh8[jf], acc[i][jf], 0, 0, 0);
                    acc[i][jf] = __builtin_amdgcn_mfma_f32_16x16x32_bf16(qa_l[ks][i], bh8[jf], acc[i][jf], 0, 0, 0);
                    acc[i][jf] = __builtin_amdgcn_mfma_f32_16x16x32_bf16(qa_h[ks][i], bl8[jf], acc[i][jf], 0, 0, 0);
                }
        }

#pragma unroll
        for (int i = 0; i < 4; ++i) { acc[i][0] *= 0.125f; acc[i][1] *= 0.125f; }

#pragma unroll
        for (int i = 0; i < 4; ++i)
#pragma unroll
            for (int r = 0; r < 4; ++r) {
                const int e = i * 4 + r;
                const float tmax = fmaxf(acc[i][0][r], acc[i][1][r]);
                const float mO = m_reg[e];
                const float mN = fmaxf(mO, tmax);
                const float s = __expf(acc[i][0][r] - mN) + __expf(acc[i][1][r] - mN);
                l_reg[e] = l_reg[e] * __expf(mO - mN) + s;
                m_reg[e] = mN;
            }
        __syncthreads();
    }

    // ------------------- reduce (m,l): lanes, then wx ---------------------
#pragma unroll
    for (int e = 0; e < 16; ++e) {
        float mm = m_reg[e], ll = l_reg[e];
#pragma unroll
        for (int off = 1; off < 16; off <<= 1) {
            const float mo = __shfl_xor(mm, off);
            const float lo = __shfl_xor(ll, off);
            const float M = fmaxf(mm, mo);
            ll = ll * __expf(mm - M) + lo * __expf(mo - M);
            mm = M;
        }
        m_reg[e] = mm; l_reg[e] = ll;
    }
    if (fr == 0) {
#pragma unroll
        for (int e = 0; e < 16; ++e) {
            const int row = wy * 64 + (e >> 2) * 16 + fg * 4 + (e & 3);
            red_m[wx][row] = m_reg[e];
            red_l[wx][row] = l_reg[e];
        }
    }
    __syncthreads();
    if (t < 128) {
        const float ma = red_m[0][t], mb = red_m[1][t];
        const float M = fmaxf(ma, mb);
        const float L = red_l[0][t] * __expf(ma - M) + red_l[1][t] * __expf(mb - M);
        sm_m[t] = M;
        sm_rl[t] = 1.0f / L;
    }
    __syncthreads();

    // ------------------------- pass B: recompute + PV ---------------------
    f32x4 oacc[4][2];
#pragma unroll
    for (int i = 0; i < 4; ++i) { oacc[i][0] = (f32x4){0,0,0,0}; oacc[i][1] = (f32x4){0,0,0,0}; }

    for (int nt = 0; nt < 32; ++nt) {
        const int j0 = nt * 64;

        // prefetch K planes
        const long gk = ((long)z * SS + j0 + krow) * 64 + kc;
        const short8 g0h = *(const short8*)&kh_hi[gk];
        const short8 g1h = *(const short8*)&kh_hi[gk + 8];
        const short8 g0l = *(const short8*)&kh_lo[gk];
        const short8 g1l = *(const short8*)&kh_lo[gk + 8];
        // prefetch V B-frags: B[n=d][k=j], 16B contiguous in s (L2-hot)
        short8 vb_h[2][2], vb_l[2][2];
#pragma unroll
        for (int nb = 0; nb < 2; ++nb)
#pragma unroll
            for (int ks = 0; ks < 2; ++ks) {
                const long gv = ((long)z * 64 + wx * 32 + nb * 16 + fr) * SS + j0 + ks * 32 + fg * 8;
                vb_h[nb][ks] = *(const short8*)&vt_hi[gv];
                vb_l[nb][ks] = *(const short8*)&vt_lo[gv];
            }

        *(short8*)&Kh[swz(krow, kc)]     = g0h;
        *(short8*)&Kh[swz(krow, kc + 8)] = g1h;
        *(short8*)&Kl[swz(krow, kc)]     = g0l;
        *(short8*)&Kl[swz(krow, kc + 8)] = g1l;
        __syncthreads();   // K ready (also: all waves past prev PV -> Pb free)

        // ---- recompute S tile (bitwise-identical to pass A) ----
        f32x4 acc[4][2];
#pragma unroll
        for (int i = 0; i < 4; ++i) { acc[i][0] = (f32x4){0,0,0,0}; acc[i][1] = (f32x4){0,0,0,0}; }
#pragma unroll
        for (int ks = 0; ks < 2; ++ks) {
            const int fk = ks * 32 + fg * 8;
            short8 bh8[2], bl8[2];
#pragma unroll
            for (int jf = 0; jf < 2; ++jf) {
                const int idx = swz(wx * 32 + jf * 16 + fr, fk);
                bh8[jf] = *(const short8*)&Kh[idx];
                bl8[jf] = *(const short8*)&Kl[idx];
            }
#pragma unroll
            for (int i = 0; i < 4; ++i)
#pragma unroll
                for (int jf = 0; jf < 2; ++jf) {
                    acc[i][jf] = __builtin_amdgcn_mfma_f32_16x16x32_bf16(qa_h[ks][i], bh8[jf], acc[i][jf], 0, 0, 0);
                    acc[i][jf] = __builtin_amdgcn_mfma_f32_16x16x32_bf16(qa_l[ks][i], bh8[jf], acc[i][jf], 0, 0, 0);
                    acc[i][jf] = __builtin_amdgcn_mfma_f32_16x16x32_bf16(qa_h[ks][i], bl8[jf], acc[i][jf], 0, 0, 0);
                }
        }

        // ---- normalize, write attn, transpose P into LDS ----
#pragma unroll
        for (int i = 0; i < 4; ++i)
#pragma unroll
            for (int r = 0; r < 4; ++r) {
                const int m_loc = wy * 64 + i * 16 + fg * 4 + r;
                const float mR = sm_m[m_loc], rR = sm_rl[m_loc];
                const long row = (long)(m0 + m_loc) * SS;
#pragma unroll
                for (int jf = 0; jf < 2; ++jf) {
                    const int j_loc = wx * 32 + jf * 16 + fr;
                    const float p = __expf(acc[i][jf][r] * 0.125f - mR) * rR;
                    __builtin_nontemporal_store(p, &attnZ[row + j0 + j_loc]);
                    unsigned short hh, ll; split2(p, hh, ll);
                    const unsigned u = (unsigned)hh | ((unsigned)ll << 16);
                    const int chunk = (j_loc >> 2) ^ (m_loc & 7);
                    Pb[m_loc * 64 + (chunk << 2) + (j_loc & 3)] = u;
                }
            }
        __syncthreads();   // P ready

        // ---- PV MFMA: A = P from LDS (unpack hi/lo), B = V frags ----
#pragma unroll
        for (int ks = 0; ks < 2; ++ks) {
            short8 ph8[4], pl8[4];
#pragma unroll
            for (int i = 0; i < 4; ++i) {
                const int ml = wy * 64 + i * 16 + fr;
                const int s8 = ml & 7;
                const int base = ml * 64;
                const int c0 = ks * 8 + fg * 2;
                const uint4 clo = *(const uint4*)&Pb[base + ((c0 ^ s8) << 2)];
                const uint4 chi = *(const uint4*)&Pb[base + (((c0 + 1) ^ s8) << 2)];
                union { short8 v; unsigned u[4]; } hh, ll;
                hh.u[0] = (clo.x & 0xffffu) | (clo.y << 16);
                hh.u[1] = (clo.z & 0xffffu) | (clo.w << 16);
                hh.u[2] = (chi.x & 0xffffu) | (chi.y << 16);
                hh.u[3] = (chi.z & 0xffffu) | (chi.w << 16);
                ll.u[0] = (clo.x >> 16) | (clo.y & 0xffff0000u);
                ll.u[1] = (clo.z >> 16) | (clo.w & 0xffff0000u);
                ll.u[2] = (chi.x >> 16) | (chi.y & 0xffff0000u);
                ll.u[3] = (chi.z >> 16) | (chi.w & 0xffff0000u);
                ph8[i] = hh.v; pl8[i] = ll.v;
            }
#pragma unroll
            for (int i = 0; i < 4; ++i)
#pragma unroll
                for (int nb = 0; nb < 2; ++nb) {
                    oacc[i][nb] = __builtin_amdgcn_mfma_f32_16x16x32_bf16(ph8[i], vb_h[nb][ks], oacc[i][nb], 0, 0, 0);
                    oacc[i][nb] = __builtin_amdgcn_mfma_f32_16x16x32_bf16(pl8[i], vb_h[nb][ks], oacc[i][nb], 0, 0, 0);
                    oacc[i][nb] = __builtin_amdgcn_mfma_f32_16x16x32_bf16(ph8[i], vb_l[nb][ks], oacc[i][nb], 0, 0, 0);
                }
        }
    }

    // ---- O epilogue -> oh [b, s, h*64+d] ----
#pragma unroll
    for (int nb = 0; nb < 2; ++nb) {
        const int d = wx * 32 + nb * 16 + fr;
#pragma unroll
        for (int i = 0; i < 4; ++i)
#pragma unroll
            for (int r = 0; r < 4; ++r) {
                const int m = m0 + wy * 64 + i * 16 + fg * 4 + r;
                oh[((long)(b * SS + m)) * D_MODEL + h * 64 + d] = oacc[i][nb][r];
            }
    }
}

// ---------------------------------------------------------------------------
extern "C" void kernel_launch(void* const* d_in, const int* in_sizes, int n_in,
                              void* d_out, int out_size, void* d_ws, size_t ws_size,
                              hipStream_t stream)
{
    const float* q  = (const float*)d_in[0];
    const float* k  = (const float*)d_in[1];
    const float* v  = (const float*)d_in[2];
    const float* wq = (const float*)d_in[3];
    const float* bq = (const float*)d_in[4];
    const float* wk = (const float*)d_in[5];
    const float* bk = (const float*)d_in[6];
    const float* wv = (const float*)d_in[7];
    const float* bv = (const float*)d_in[8];
    const float* wo = (const float*)d_in[9];
    const float* bo = (const float*)d_in[10];

    float* out  = (float*)d_out;                         // [2,2048,1024]
    float* attn = out + (long)BB * SS * D_MODEL;         // [2,16,2048,2048]

    // --- workspace layout (64 MB) ---
    char* ws = (char*)d_ws;
    unsigned short* qh_hi = (unsigned short*)ws;
    unsigned short* qh_lo = (unsigned short*)(ws + (8L  << 20));
    unsigned short* kh_hi = (unsigned short*)(ws + (16L << 20));
    unsigned short* kh_lo = (unsigned short*)(ws + (24L << 20));
    unsigned short* vt_hi = (unsigned short*)(ws + (32L << 20));
    unsigned short* vt_lo = (unsigned short*)(ws + (40L << 20));
    float*          oh    = (float*)(ws + (48L << 20));
    unsigned short* wq_hi = (unsigned short*)(ws + (48L << 20));
    unsigned short* wq_lo = (unsigned short*)(ws + (50L << 20));
    unsigned short* wk_hi = (unsigned short*)(ws + (52L << 20));
    unsigned short* wk_lo = (unsigned short*)(ws + (54L << 20));
    unsigned short* wv_hi = (unsigned short*)(ws + (56L << 20));
    unsigned short* wv_lo = (unsigned short*)(ws + (58L << 20));
    unsigned short* wo_hi = (unsigned short*)(ws);               // alias qh
    unsigned short* wo_lo = (unsigned short*)(ws + (2L << 20));  // alias qh

    const dim3 blk(256);
    const int NW4 = (D_MODEL * D_MODEL) / 4;

    hipLaunchKernelGGL(split_f32, dim3(1024), blk, 0, stream, wq, wq_hi, wq_lo, NW4);
    hipLaunchKernelGGL(split_f32, dim3(1024), blk, 0, stream, wk, wk_hi, wk_lo, NW4);
    hipLaunchKernelGGL(split_f32, dim3(1024), blk, 0, stream, wv, wv_hi, wv_lo, NW4);

    // Projections: M=4096, N=1024, K=1024 -> split planes (q,k) / split-T (v)
    const dim3 gproj(D_MODEL / 128, M_TOT / 128, 1);
    hipLaunchKernelGGL((gemm3<2, true>), gproj, blk, 0, stream,
                       q, D_MODEL, wq_hi, wq_lo, D_MODEL, bq,
                       (float*)nullptr, qh_hi, qh_lo, 0, D_MODEL);
    hipLaunchKernelGGL((gemm3<2, true>), gproj, blk, 0, stream,
                       k, D_MODEL, wk_hi, wk_lo, D_MODEL, bk,
                       (float*)nullptr, kh_hi, kh_lo, 0, D_MODEL);
    hipLaunchKernelGGL((gemm3<3, true>), gproj, blk, 0, stream,
                       v, D_MODEL, wv_hi, wv_lo, D_MODEL, bv,
                       (float*)nullptr, vt_hi, vt_lo, 0, D_MODEL);

    // Fused scores+softmax+PV (recompute, no S spill)
    hipLaunchKernelGGL(attn_fused, dim3(BB * N_HEADS, SS / 128), blk, 0, stream,
                       qh_hi, qh_lo, kh_hi, kh_lo, vt_hi, vt_lo, attn, oh);

    // Split wo into the (now dead) qh region.
    hipLaunchKernelGGL(split_f32, dim3(1024), blk, 0, stream, wo, wo_hi, wo_lo, NW4);

    // Output projection: oh @ wo^T + bo -> out
    hipLaunchKernelGGL((gemm3<0, true>), gproj, blk, 0, stream,
                       oh, D_MODEL, wo_hi, wo_lo, D_MODEL, bo,
                       out, (unsigned short*)nullptr, (unsigned short*)nullptr,
                       D_MODEL, D_MODEL);
}